// Round 2
// baseline (402.181 us; speedup 1.0000x reference)
//
#include <hip/hip_runtime.h>
#include <hip/hip_bf16.h>

#define B_ 8
#define S_ 2048
#define H_ 4096
#define D_ 128
#define NS_ 128
#define KS 32            /* split-K for kgemm: KC = 128 h per block */
#define KC (H_ / KS)
#define KSQ 8            /* split-K for qproj */

typedef _Float16 half8 __attribute__((ext_vector_type(8)));
typedef float floatx4 __attribute__((ext_vector_type(4)));

// ---------------------------------------------------------------------------
// Workspace (byte offsets):
//   idx    : int[1024]             @ 0         (4 KB)
//   Bp_hi  : half8[65536]          @ 4096      (1 MB)  Wk in MFMA-frag order
//   Bp_lo  : half8[65536]          @ 1052672   (1 MB)
//   k_part : float[KS][B][NS][D]   @ 2101248   (16 MB)
//   q_part : float[KSQ][B][D]      @ +         (32 KB)
//   v_part : float[KS][B][NS]      @ +         (128 KB)
//   logits : float[B][NS], v_red : float[B][NS]
// every element written before read (ws poisoned 0xAA).
// Bp index: (((kc*2 + c)*2 + k0)*8 + dt)*64 + quad*16 + mrow
//   holds Wk[d = dt*16+mrow][h = kc*128 + c*64 + (k0*4+quad)*8 .. +8]
// so a wave's B-frag load is base + lane*16B — perfectly coalesced, L2-hot.
//
// R1 change: kgemm main grid 256 -> 512 blocks (64 tokens/block instead of
// 128) to double occupancy on the latency-bound hs gather. LDS 32->16 KB.
// ---------------------------------------------------------------------------

__device__ inline void cvt8(const float* x, half8* hi, half8* lo) {
    half8 h, l;
    #pragma unroll
    for (int j = 0; j < 8; ++j) {
        _Float16 hh = (_Float16)x[j];
        h[j] = hh;
        l[j] = (_Float16)(x[j] - (float)hh);
    }
    *hi = h; *lo = l;
}

__device__ inline floatx4 mfma16(half8 a, half8 b, floatx4 c) {
    return __builtin_amdgcn_mfma_f32_16x16x32_f16(a, b, c, 0, 0, 0);
}

// Kernel 1: blocks 0..7: extract per-row sorted positions of mask==1.
//           blocks 8..39: pre-convert+pack Wk into frag-ordered f16 hi/lo.
__global__ __launch_bounds__(256) void prep_kernel(
    const float* __restrict__ Wk, const int* __restrict__ mask,
    int* __restrict__ idx, half8* __restrict__ Bp_hi, half8* __restrict__ Bp_lo)
{
    int bid = blockIdx.x;
    int tid = threadIdx.x;
    if (bid >= 8) {
        // ---- Wk pack: one kc slice (128 d x 128 h) per block ----
        int kc = bid - 8;
        int d  = tid >> 1;          // 0..127
        int hh = tid & 1;           // chunk c
        const float* src = Wk + (size_t)d * H_ + kc * KC + hh * 64;
        int dt = d >> 4, mrow = d & 15;
        #pragma unroll
        for (int z = 0; z < 8; ++z) {
            float x[8];
            *(float4*)&x[0] = *(const float4*)(src + z * 8);
            *(float4*)&x[4] = *(const float4*)(src + z * 8 + 4);
            half8 hi, lo; cvt8(x, &hi, &lo);
            int k0 = z >> 2, quad = z & 3;
            int o = (((kc * 2 + hh) * 2 + k0) * 8 + dt) * 64 + quad * 16 + mrow;
            Bp_hi[o] = hi; Bp_lo[o] = lo;
        }
        return;
    }
    int b = bid;
    const int* mrow = mask + b * S_;
    __shared__ int wsum[4];
    int lane = tid & 63, wave = tid >> 6;
    int base = 0;
    for (int c = 0; c < S_ / 256; ++c) {
        int s = c * 256 + tid;
        int mv = mrow[s];
        unsigned long long bal = __ballot(mv != 0);
        int pre = __popcll(bal & ((1ull << lane) - 1ull));
        __syncthreads();
        if (lane == 0) wsum[wave] = __popcll(bal);
        __syncthreads();
        int woff = 0, tot = 0;
        #pragma unroll
        for (int w = 0; w < 4; ++w) { if (w < wave) woff += wsum[w]; tot += wsum[w]; }
        if (mv) idx[b * NS_ + base + woff + pre] = s;
        base += tot;
    }
}

// Kernel 2: blocks 0..511: gathered K-projection via f16x3 MFMA, split-K 32,
//           token-split 2 (64 tokens per block), B-frags direct from
//           pre-packed global (no LDS), exact-fp32 v-projection folded in.
//           Blocks 512..575: q GEMV (split-K 8).
__global__ __launch_bounds__(256) void kgemm_kernel(
    const float* __restrict__ hs,
    const half8* __restrict__ Bp_hi, const half8* __restrict__ Bp_lo,
    const float* __restrict__ Wq, const float* __restrict__ Wr,
    const int* __restrict__ idx,
    float* __restrict__ k_part, float* __restrict__ v_part,
    float* __restrict__ q_part)
{
    __shared__ __align__(16) char smem[16384];
    int tid = threadIdx.x;
    int bid = blockIdx.x;

    if (bid >= 512) {
        // ---- q projection for the last selected token ----
        int qb = bid - 512;
        int b  = qb >> 3;
        int kc = qb & 7;
        float* hsrow = (float*)smem;            // 2 KB
        float* qred  = (float*)(smem + 2048);   // 512 B
        int ilast = idx[b * NS_ + NS_ - 1];
        const float* rp = hs + ((size_t)(b * S_ + ilast)) * H_ + kc * 512;
        if (tid < 128) ((float4*)hsrow)[tid] = ((const float4*)rp)[tid];
        __syncthreads();
        int d = tid & 127, half = tid >> 7;
        const float* wq = Wq + (size_t)d * H_ + kc * 512 + half * 256;
        const float* hh = hsrow + half * 256;
        float acc = 0.f;
        #pragma unroll 8
        for (int h = 0; h < 256; h += 4) {
            float4 w = *(const float4*)(wq + h);
            acc += hh[h] * w.x + hh[h + 1] * w.y + hh[h + 2] * w.z + hh[h + 3] * w.w;
        }
        if (half) qred[d] = acc;
        __syncthreads();
        if (!half) q_part[(kc * B_ + b) * D_ + d] = acc + qred[d];
        return;
    }

    int b  = bid >> 6;           // 0..7
    int kc = (bid >> 1) & 31;    // 0..31
    int th = bid & 1;            // token half: 0 -> tokens 0..63, 1 -> 64..127

    half8* AhS = (half8*)smem;                  // [8 kg][64 tok] : 8 KB
    half8* AlS = (half8*)(smem + 8192);         // 8 KB

    int ia   = tid & 63;         // token within half (0..63)
    int half = tid >> 6;         // 0..3 : 16-float segment of each 64-h chunk
    int row  = idx[b * NS_ + th * 64 + ia];
    const float* ap  = hs + ((size_t)(b * S_ + row)) * H_ + kc * KC;
    const float* wrp = Wr + kc * KC;

    int lane = tid & 63, w = tid >> 6;
    int quad = lane >> 4, mrow = lane & 15;
    int TB = (w >> 1) * 32;      // wave token base (0 or 32)
    int DB = (w & 1) * 64;       // wave d base

    floatx4 acc[2][4];
    #pragma unroll
    for (int i = 0; i < 2; ++i)
        #pragma unroll
        for (int j = 0; j < 4; ++j) acc[i][j] = (floatx4){0.f, 0.f, 0.f, 0.f};
    float vacc = 0.f;

    #pragma unroll
    for (int c = 0; c < 2; ++c) {               // two 64-h chunks
        // ---- stage A (hi/lo f16) + exact v partial ----
        #pragma unroll
        for (int g = 0; g < 2; ++g) {
            float x[8], wv[8];
            *(float4*)&x[0]  = *(const float4*)(ap + c * 64 + half * 16 + g * 8);
            *(float4*)&x[4]  = *(const float4*)(ap + c * 64 + half * 16 + g * 8 + 4);
            *(float4*)&wv[0] = *(const float4*)(wrp + c * 64 + half * 16 + g * 8);
            *(float4*)&wv[4] = *(const float4*)(wrp + c * 64 + half * 16 + g * 8 + 4);
            #pragma unroll
            for (int j = 0; j < 8; ++j) vacc += x[j] * wv[j];
            half8 hi, lo; cvt8(x, &hi, &lo);
            AhS[(half * 2 + g) * 64 + ia] = hi;
            AlS[(half * 2 + g) * 64 + ia] = lo;
        }
        __syncthreads();

        // ---- MFMA: per k0, A-frags from LDS, B-frags direct from global ----
        #pragma unroll
        for (int k0 = 0; k0 < 2; ++k0) {
            int kb = (k0 * 4 + quad) * 64;
            int boff = (((kc * 2 + c) * 2 + k0) * 8 + (DB >> 4)) * 64 + lane;
            half8 ah[2], al[2], bh[4], bl[4];
            #pragma unroll
            for (int i = 0; i < 4; ++i) {
                bh[i] = Bp_hi[boff + i * 64];
                bl[i] = Bp_lo[boff + i * 64];
            }
            #pragma unroll
            for (int i = 0; i < 2; ++i) {
                ah[i] = AhS[kb + TB + i * 16 + mrow];
                al[i] = AlS[kb + TB + i * 16 + mrow];
            }
            #pragma unroll
            for (int mt = 0; mt < 2; ++mt)
                #pragma unroll
                for (int nt = 0; nt < 4; ++nt) {
                    acc[mt][nt] = mfma16(ah[mt], bh[nt], acc[mt][nt]);
                    acc[mt][nt] = mfma16(ah[mt], bl[nt], acc[mt][nt]);
                    acc[mt][nt] = mfma16(al[mt], bh[nt], acc[mt][nt]);
                }
        }
        __syncthreads();
    }

    // ---- epilogue: write k_part in [tok][d] layout per C/D mapping ----
    float* kp = k_part + (size_t)(kc * B_ + b) * NS_ * D_ + (size_t)th * 64 * D_;
    #pragma unroll
    for (int mt = 0; mt < 2; ++mt)
        #pragma unroll
        for (int nt = 0; nt < 4; ++nt)
            #pragma unroll
            for (int r = 0; r < 4; ++r) {
                int tok = TB + mt * 16 + quad * 4 + r;
                int d   = DB + nt * 16 + mrow;
                kp[tok * D_ + d] = acc[mt][nt][r];
            }

    // ---- v reduce (reuse smem; frag reads are behind the last barrier) ----
    float* vb = (float*)smem;
    vb[half * 64 + ia] = vacc;
    __syncthreads();
    if (tid < 64)
        v_part[(kc * B_ + b) * NS_ + th * 64 + tid] =
            vb[tid] + vb[64 + tid] + vb[128 + tid] + vb[192 + tid];
}

// Kernel 3: per (b, 8-token chunk): reduce q/k/v partials, RoPE, logits.
__global__ __launch_bounds__(256) void logit_kernel(
    const float* __restrict__ k_part, const float* __restrict__ q_part,
    const float* __restrict__ v_part,
    const float* __restrict__ bq, const float* __restrict__ bk,
    const float* __restrict__ br,
    float* __restrict__ logits, float* __restrict__ v_red)
{
    int b  = blockIdx.x >> 4;
    int tc = blockIdx.x & 15;
    int tid = threadIdx.x;
    __shared__ float qtmp[2][D_];
    __shared__ float qr[D_];
    __shared__ float lred[8][32];

    {
        int d = tid & 127, hf = tid >> 7;
        float qv = hf ? 0.f : bq[d];
        #pragma unroll
        for (int kc = 0; kc < 4; ++kc) qv += q_part[((hf * 4 + kc) * B_ + b) * D_ + d];
        qtmp[hf][d] = qv;
    }
    int vt = tid >> 5, vkc = tid & 31;
    float vv = v_part[(vkc * B_ + b) * NS_ + tc * 8 + vt];
    __syncthreads();

    if (tid < 128) {
        int i = tid >> 1;
        float x0 = qtmp[0][2 * i] + qtmp[1][2 * i];
        float x1 = qtmp[0][2 * i + 1] + qtmp[1][2 * i + 1];
        float fr = 1.0f / powf(10000.0f, (float)(2 * i) / 128.0f);
        float s, c; sincosf(127.0f * fr, &s, &c);
        qr[tid] = (tid & 1) ? (x0 * s + x1 * c) : (x0 * c - x1 * s);
    }
    lred[vt][vkc] = vv;
    __syncthreads();
    if (tid < 8) {
        float s = br[0];
        #pragma unroll
        for (int j = 0; j < 32; ++j) s += lred[tid][j];
        v_red[b * NS_ + tc * 8 + tid] = s;
    }

    int tok = tid >> 5, q4 = tid & 31;
    int tg  = tc * 8 + tok;
    float4 kv = make_float4(0.f, 0.f, 0.f, 0.f);
    #pragma unroll 8
    for (int kc = 0; kc < KS; ++kc) {
        float4 x = *(const float4*)(k_part + ((size_t)(kc * B_ + b) * NS_ + tg) * D_ + q4 * 4);
        kv.x += x.x; kv.y += x.y; kv.z += x.z; kv.w += x.w;
    }
    kv.x += bk[4 * q4 + 0]; kv.y += bk[4 * q4 + 1];
    kv.z += bk[4 * q4 + 2]; kv.w += bk[4 * q4 + 3];
    float fr0 = 1.0f / powf(10000.0f, (float)(4 * q4) / 128.0f);
    float fr1 = 1.0f / powf(10000.0f, (float)(4 * q4 + 2) / 128.0f);
    float s0, c0, s1, c1;
    sincosf((float)tg * fr0, &s0, &c0);
    sincosf((float)tg * fr1, &s1, &c1);
    float k0 = kv.x * c0 - kv.y * s0;
    float k1 = kv.x * s0 + kv.y * c0;
    float k2 = kv.z * c1 - kv.w * s1;
    float k3 = kv.z * s1 + kv.w * c1;
    float part = k0 * qr[4 * q4] + k1 * qr[4 * q4 + 1]
               + k2 * qr[4 * q4 + 2] + k3 * qr[4 * q4 + 3];
    __syncthreads();
    lred[tok][q4] = part;
    __syncthreads();
    if (tid < 8) {
        float s = 0.f;
        #pragma unroll
        for (int j = 0; j < 32; ++j) s += lred[tid][j];
        logits[b * NS_ + tc * 8 + tid] = s * 0.08838834764831845f;
    }
}

// Kernel 4: per-b softmax + first-difference + outputs.
__global__ __launch_bounds__(128) void softmax_kernel(
    const float* __restrict__ logits, const float* __restrict__ v_red,
    float* __restrict__ out)
{
    int b = blockIdx.x;
    int t = threadIdx.x;
    __shared__ float red[128];
    __shared__ float vsh[128];

    float logit = logits[b * NS_ + t];
    vsh[t] = v_red[b * NS_ + t];
    red[t] = logit;
    __syncthreads();
    float sr = (t == 0) ? vsh[0] : vsh[t] - vsh[t - 1];
    #pragma unroll
    for (int off = 64; off > 0; off >>= 1) {
        if (t < off) red[t] = fmaxf(red[t], red[t + off]);
        __syncthreads();
    }
    float mx = red[0];
    __syncthreads();
    float e = expf(logit - mx);
    red[t] = e;
    __syncthreads();
    #pragma unroll
    for (int off = 64; off > 0; off >>= 1) {
        if (t < off) red[t] += red[t + off];
        __syncthreads();
    }
    float attn = e / red[0];
    out[b * NS_ + t] = sr * attn;
    __syncthreads();
    red[t] = attn * sr;
    __syncthreads();
    #pragma unroll
    for (int off = 64; off > 0; off >>= 1) {
        if (t < off) red[t] += red[t + off];
        __syncthreads();
    }
    if (t == 0) out[B_ * NS_ + b] = red[0];
}

extern "C" void kernel_launch(void* const* d_in, const int* in_sizes, int n_in,
                              void* d_out, int out_size, void* d_ws, size_t ws_size,
                              hipStream_t stream) {
    const float* hs   = (const float*)d_in[0];
    const int*   mask = (const int*)d_in[1];
    const float* Wq = (const float*)d_in[3];
    const float* bq = (const float*)d_in[4];
    const float* Wk = (const float*)d_in[5];
    const float* bk = (const float*)d_in[6];
    const float* Wr = (const float*)d_in[7];
    const float* br = (const float*)d_in[8];
    float* out = (float*)d_out;

    char* wsb = (char*)d_ws;
    int*   idx    = (int*)wsb;                              // 4 KB
    half8* Bp_hi  = (half8*)(wsb + 4096);                   // 1 MB
    half8* Bp_lo  = (half8*)(wsb + 4096 + 1048576);         // 1 MB
    float* k_part = (float*)(wsb + 4096 + 2097152);         // 16 MB
    float* q_part = k_part + (size_t)KS * B_ * NS_ * D_;
    float* v_part = q_part + (size_t)KSQ * B_ * D_;
    float* logits = v_part + (size_t)KS * B_ * NS_;
    float* v_red  = logits + B_ * NS_;

    prep_kernel   <<<40,  256, 0, stream>>>(Wk, mask, idx, Bp_hi, Bp_lo);
    kgemm_kernel  <<<576, 256, 0, stream>>>(hs, Bp_hi, Bp_lo, Wq, Wr, idx, k_part, v_part, q_part);
    logit_kernel  <<<128, 256, 0, stream>>>(k_part, q_part, v_part, bq, bk, br, logits, v_red);
    softmax_kernel<<<8,   128, 0, stream>>>(logits, v_red, out);
}

// Round 4
// 335.829 us; speedup vs baseline: 1.1976x; 1.1976x over previous
//
#include <hip/hip_runtime.h>
#include <hip/hip_bf16.h>

#define B_ 8
#define S_ 2048
#define H_ 4096
#define D_ 128
#define NS_ 128
#define KS 16            /* split-K for kgemm: KC = 256 h per block */
#define KC (H_ / KS)
#define KSQ 8            /* split-K for qproj */

typedef _Float16 half8 __attribute__((ext_vector_type(8)));
typedef float floatx4 __attribute__((ext_vector_type(4)));

// ---------------------------------------------------------------------------
// Workspace (byte offsets):
//   idx    : int[1024]             @ 0         (4 KB)
//   Bp_hi  : half8[65536]          @ 4096      (1 MB)  Wk in MFMA-frag order
//   Bp_lo  : half8[65536]          @ 1052672   (1 MB)
//   k_part : float[B][NS][KS][D]   @ 2101248   (8 MB)   <-- R3: [b][tok][kc][d]
//   q_part : float[KSQ][B][D]      @ +         (32 KB)
//   v_part : float[KS][B][NS]      @ +         (64 KB)
//   logits : float[B][NS], v_red : float[B][NS]
// every element written before read (ws poisoned 0xAA).
// Bp index: ((g64*2 + k0)*8 + dt)*64 + quad*16 + mrow   (g64 = 64-h chunk 0..63)
//   holds Wk[d = dt*16+mrow][h = g64*64 + (k0*4+quad)*8 .. +8]
// so a wave's B-frag load is base + lane*16B — perfectly coalesced, L2-hot.
//
// R3 changes: KS 32->16 (k_part 16->8 MB, kgemm per-block MFMA x2, logit
// combine depth /2); k_part layout [b][tok][kc][d] so the logit combine
// reads one contiguous 8 KB region per token.
// ---------------------------------------------------------------------------

__device__ inline void cvt8(const float* x, half8* hi, half8* lo) {
    half8 h, l;
    #pragma unroll
    for (int j = 0; j < 8; ++j) {
        _Float16 hh = (_Float16)x[j];
        h[j] = hh;
        l[j] = (_Float16)(x[j] - (float)hh);
    }
    *hi = h; *lo = l;
}

__device__ inline floatx4 mfma16(half8 a, half8 b, floatx4 c) {
    return __builtin_amdgcn_mfma_f32_16x16x32_f16(a, b, c, 0, 0, 0);
}

// Kernel 1: blocks 0..7: extract per-row sorted positions of mask==1.
//           blocks 8..39: pre-convert+pack Wk into frag-ordered f16 hi/lo.
__global__ __launch_bounds__(256) void prep_kernel(
    const float* __restrict__ Wk, const int* __restrict__ mask,
    int* __restrict__ idx, half8* __restrict__ Bp_hi, half8* __restrict__ Bp_lo)
{
    int bid = blockIdx.x;
    int tid = threadIdx.x;
    if (bid >= 8) {
        // ---- Wk pack: one 128-h slice (128 d x 128 h) per block ----
        int kc = bid - 8;           // 0..31 (128-h granularity)
        int d  = tid >> 1;          // 0..127
        int hh = tid & 1;           // 64-h chunk within the 128
        const float* src = Wk + (size_t)d * H_ + kc * 128 + hh * 64;
        int dt = d >> 4, mrow = d & 15;
        #pragma unroll
        for (int z = 0; z < 8; ++z) {
            float x[8];
            *(float4*)&x[0] = *(const float4*)(src + z * 8);
            *(float4*)&x[4] = *(const float4*)(src + z * 8 + 4);
            half8 hi, lo; cvt8(x, &hi, &lo);
            int k0 = z >> 2, quad = z & 3;
            int g64 = kc * 2 + hh;  // global 64-h chunk 0..63
            int o = ((g64 * 2 + k0) * 8 + dt) * 64 + quad * 16 + mrow;
            Bp_hi[o] = hi; Bp_lo[o] = lo;
        }
        return;
    }
    int b = bid;
    const int* mrow = mask + b * S_;
    __shared__ int wsum[4];
    int lane = tid & 63, wave = tid >> 6;
    int base = 0;
    for (int c = 0; c < S_ / 256; ++c) {
        int s = c * 256 + tid;
        int mv = mrow[s];
        unsigned long long bal = __ballot(mv != 0);
        int pre = __popcll(bal & ((1ull << lane) - 1ull));
        __syncthreads();
        if (lane == 0) wsum[wave] = __popcll(bal);
        __syncthreads();
        int woff = 0, tot = 0;
        #pragma unroll
        for (int w = 0; w < 4; ++w) { if (w < wave) woff += wsum[w]; tot += wsum[w]; }
        if (mv) idx[b * NS_ + base + woff + pre] = s;
        base += tot;
    }
}

// Kernel 2: blocks 0..255: gathered K-projection via f16x3 MFMA, split-K 16,
//           token-split 2 (64 tokens per block), B-frags direct from
//           pre-packed global (no LDS), exact-fp32 v-projection folded in.
//           Blocks 256..319: q GEMV (split-K 8).
__global__ __launch_bounds__(256) void kgemm_kernel(
    const float* __restrict__ hs,
    const half8* __restrict__ Bp_hi, const half8* __restrict__ Bp_lo,
    const float* __restrict__ Wq, const float* __restrict__ Wr,
    const int* __restrict__ idx,
    float* __restrict__ k_part, float* __restrict__ v_part,
    float* __restrict__ q_part)
{
    __shared__ __align__(16) char smem[16384];
    int tid = threadIdx.x;
    int bid = blockIdx.x;

    if (bid >= 256) {
        // ---- q projection for the last selected token ----
        int qb = bid - 256;
        int b  = qb >> 3;
        int kc = qb & 7;
        float* hsrow = (float*)smem;            // 2 KB
        float* qred  = (float*)(smem + 2048);   // 512 B
        int ilast = idx[b * NS_ + NS_ - 1];
        const float* rp = hs + ((size_t)(b * S_ + ilast)) * H_ + kc * 512;
        if (tid < 128) ((float4*)hsrow)[tid] = ((const float4*)rp)[tid];
        __syncthreads();
        int d = tid & 127, half = tid >> 7;
        const float* wq = Wq + (size_t)d * H_ + kc * 512 + half * 256;
        const float* hh = hsrow + half * 256;
        float acc = 0.f;
        #pragma unroll 8
        for (int h = 0; h < 256; h += 4) {
            float4 w = *(const float4*)(wq + h);
            acc += hh[h] * w.x + hh[h + 1] * w.y + hh[h + 2] * w.z + hh[h + 3] * w.w;
        }
        if (half) qred[d] = acc;
        __syncthreads();
        if (!half) q_part[(kc * B_ + b) * D_ + d] = acc + qred[d];
        return;
    }

    int b  = bid >> 5;           // 0..7
    int kc = (bid >> 1) & 15;    // 0..15 (256-h slice)
    int th = bid & 1;            // token half: 0 -> tokens 0..63, 1 -> 64..127

    half8* AhS = (half8*)smem;                  // [8 kg][64 tok] : 8 KB
    half8* AlS = (half8*)(smem + 8192);         // 8 KB

    int ia   = tid & 63;         // token within half (0..63)
    int half = tid >> 6;         // 0..3 : 16-float segment of each 64-h chunk
    int row  = idx[b * NS_ + th * 64 + ia];
    const float* ap  = hs + ((size_t)(b * S_ + row)) * H_ + kc * KC;
    const float* wrp = Wr + kc * KC;

    int lane = tid & 63, w = tid >> 6;
    int quad = lane >> 4, mrow = lane & 15;
    int TB = (w >> 1) * 32;      // wave token base (0 or 32)
    int DB = (w & 1) * 64;       // wave d base

    floatx4 acc[2][4];
    #pragma unroll
    for (int i = 0; i < 2; ++i)
        #pragma unroll
        for (int j = 0; j < 4; ++j) acc[i][j] = (floatx4){0.f, 0.f, 0.f, 0.f};
    float vacc = 0.f;

    #pragma unroll
    for (int c = 0; c < 4; ++c) {               // four 64-h chunks (KC=256)
        // ---- stage A (hi/lo f16) + exact v partial ----
        #pragma unroll
        for (int g = 0; g < 2; ++g) {
            float x[8], wv[8];
            *(float4*)&x[0]  = *(const float4*)(ap + c * 64 + half * 16 + g * 8);
            *(float4*)&x[4]  = *(const float4*)(ap + c * 64 + half * 16 + g * 8 + 4);
            *(float4*)&wv[0] = *(const float4*)(wrp + c * 64 + half * 16 + g * 8);
            *(float4*)&wv[4] = *(const float4*)(wrp + c * 64 + half * 16 + g * 8 + 4);
            #pragma unroll
            for (int j = 0; j < 8; ++j) vacc += x[j] * wv[j];
            half8 hi, lo; cvt8(x, &hi, &lo);
            AhS[(half * 2 + g) * 64 + ia] = hi;
            AlS[(half * 2 + g) * 64 + ia] = lo;
        }
        __syncthreads();

        // ---- MFMA: per k0, A-frags from LDS, B-frags direct from global ----
        int g64 = kc * 4 + c;    // global 64-h chunk
        #pragma unroll
        for (int k0 = 0; k0 < 2; ++k0) {
            int kb = (k0 * 4 + quad) * 64;
            int boff = ((g64 * 2 + k0) * 8 + (DB >> 4)) * 64 + lane;
            half8 ah[2], al[2], bh[4], bl[4];
            #pragma unroll
            for (int i = 0; i < 4; ++i) {
                bh[i] = Bp_hi[boff + i * 64];
                bl[i] = Bp_lo[boff + i * 64];
            }
            #pragma unroll
            for (int i = 0; i < 2; ++i) {
                ah[i] = AhS[kb + TB + i * 16 + mrow];
                al[i] = AlS[kb + TB + i * 16 + mrow];
            }
            #pragma unroll
            for (int mt = 0; mt < 2; ++mt)
                #pragma unroll
                for (int nt = 0; nt < 4; ++nt) {
                    acc[mt][nt] = mfma16(ah[mt], bh[nt], acc[mt][nt]);
                    acc[mt][nt] = mfma16(ah[mt], bl[nt], acc[mt][nt]);
                    acc[mt][nt] = mfma16(al[mt], bh[nt], acc[mt][nt]);
                }
        }
        __syncthreads();
    }

    // ---- epilogue: write k_part [b][tok][kc][d] per C/D mapping ----
    #pragma unroll
    for (int mt = 0; mt < 2; ++mt)
        #pragma unroll
        for (int nt = 0; nt < 4; ++nt)
            #pragma unroll
            for (int r = 0; r < 4; ++r) {
                int tok = TB + mt * 16 + quad * 4 + r;
                int d   = DB + nt * 16 + mrow;
                int tg  = th * 64 + tok;
                k_part[(((size_t)(b * NS_ + tg)) * KS + kc) * D_ + d] = acc[mt][nt][r];
            }

    // ---- v reduce (reuse smem; frag reads are behind the last barrier) ----
    float* vb = (float*)smem;
    vb[half * 64 + ia] = vacc;
    __syncthreads();
    if (tid < 64)
        v_part[(kc * B_ + b) * NS_ + th * 64 + tid] =
            vb[tid] + vb[64 + tid] + vb[128 + tid] + vb[192 + tid];
}

// Kernel 3: per (b, 8-token chunk): reduce q/k/v partials, RoPE, logits.
__global__ __launch_bounds__(256) void logit_kernel(
    const float* __restrict__ k_part, const float* __restrict__ q_part,
    const float* __restrict__ v_part,
    const float* __restrict__ bq, const float* __restrict__ bk,
    const float* __restrict__ br,
    float* __restrict__ logits, float* __restrict__ v_red)
{
    int b  = blockIdx.x >> 4;
    int tc = blockIdx.x & 15;
    int tid = threadIdx.x;
    __shared__ float qtmp[2][D_];
    __shared__ float qr[D_];
    __shared__ float lred[8][32];

    {
        int d = tid & 127, hf = tid >> 7;
        float qv = hf ? 0.f : bq[d];
        #pragma unroll
        for (int kc = 0; kc < 4; ++kc) qv += q_part[((hf * 4 + kc) * B_ + b) * D_ + d];
        qtmp[hf][d] = qv;
    }
    int vt = (tid >> 4) & 7, vkc = tid & 15;
    float vv = 0.f;
    if (tid < 128) vv = v_part[(vkc * B_ + b) * NS_ + tc * 8 + vt];
    __syncthreads();

    if (tid < 128) {
        int i = tid >> 1;
        float x0 = qtmp[0][2 * i] + qtmp[1][2 * i];
        float x1 = qtmp[0][2 * i + 1] + qtmp[1][2 * i + 1];
        float fr = 1.0f / powf(10000.0f, (float)(2 * i) / 128.0f);
        float s, c; sincosf(127.0f * fr, &s, &c);
        qr[tid] = (tid & 1) ? (x0 * s + x1 * c) : (x0 * c - x1 * s);
        lred[vt][vkc] = vv;
    }
    __syncthreads();
    if (tid < 8) {
        float s = br[0];
        #pragma unroll
        for (int j = 0; j < 16; ++j) s += lred[tid][j];
        v_red[b * NS_ + tc * 8 + tid] = s;
    }

    int tok = tid >> 5, q4 = tid & 31;
    int tg  = tc * 8 + tok;
    float4 kv = make_float4(0.f, 0.f, 0.f, 0.f);
    #pragma unroll 8
    for (int kc = 0; kc < KS; ++kc) {
        float4 x = *(const float4*)(k_part + (((size_t)(b * NS_ + tg)) * KS + kc) * D_ + q4 * 4);
        kv.x += x.x; kv.y += x.y; kv.z += x.z; kv.w += x.w;
    }
    kv.x += bk[4 * q4 + 0]; kv.y += bk[4 * q4 + 1];
    kv.z += bk[4 * q4 + 2]; kv.w += bk[4 * q4 + 3];
    float fr0 = 1.0f / powf(10000.0f, (float)(4 * q4) / 128.0f);
    float fr1 = 1.0f / powf(10000.0f, (float)(4 * q4 + 2) / 128.0f);
    float s0, c0, s1, c1;
    sincosf((float)tg * fr0, &s0, &c0);
    sincosf((float)tg * fr1, &s1, &c1);
    float k0 = kv.x * c0 - kv.y * s0;
    float k1 = kv.x * s0 + kv.y * c0;
    float k2 = kv.z * c1 - kv.w * s1;
    float k3 = kv.z * s1 + kv.w * c1;
    float part = k0 * qr[4 * q4] + k1 * qr[4 * q4 + 1]
               + k2 * qr[4 * q4 + 2] + k3 * qr[4 * q4 + 3];
    __syncthreads();
    lred[tok][q4] = part;
    __syncthreads();
    if (tid < 8) {
        float s = 0.f;
        #pragma unroll
        for (int j = 0; j < 32; ++j) s += lred[tid][j];
        logits[b * NS_ + tc * 8 + tid] = s * 0.08838834764831845f;
    }
}

// Kernel 4: per-b softmax + first-difference + outputs.
__global__ __launch_bounds__(128) void softmax_kernel(
    const float* __restrict__ logits, const float* __restrict__ v_red,
    float* __restrict__ out)
{
    int b = blockIdx.x;
    int t = threadIdx.x;
    __shared__ float red[128];
    __shared__ float vsh[128];

    float logit = logits[b * NS_ + t];
    vsh[t] = v_red[b * NS_ + t];
    red[t] = logit;
    __syncthreads();
    float sr = (t == 0) ? vsh[0] : vsh[t] - vsh[t - 1];
    #pragma unroll
    for (int off = 64; off > 0; off >>= 1) {
        if (t < off) red[t] = fmaxf(red[t], red[t + off]);
        __syncthreads();
    }
    float mx = red[0];
    __syncthreads();
    float e = expf(logit - mx);
    red[t] = e;
    __syncthreads();
    #pragma unroll
    for (int off = 64; off > 0; off >>= 1) {
        if (t < off) red[t] += red[t + off];
        __syncthreads();
    }
    float attn = e / red[0];
    out[b * NS_ + t] = sr * attn;
    __syncthreads();
    red[t] = attn * sr;
    __syncthreads();
    #pragma unroll
    for (int off = 64; off > 0; off >>= 1) {
        if (t < off) red[t] += red[t + off];
        __syncthreads();
    }
    if (t == 0) out[B_ * NS_ + b] = red[0];
}

extern "C" void kernel_launch(void* const* d_in, const int* in_sizes, int n_in,
                              void* d_out, int out_size, void* d_ws, size_t ws_size,
                              hipStream_t stream) {
    const float* hs   = (const float*)d_in[0];
    const int*   mask = (const int*)d_in[1];
    const float* Wq = (const float*)d_in[3];
    const float* bq = (const float*)d_in[4];
    const float* Wk = (const float*)d_in[5];
    const float* bk = (const float*)d_in[6];
    const float* Wr = (const float*)d_in[7];
    const float* br = (const float*)d_in[8];
    float* out = (float*)d_out;

    char* wsb = (char*)d_ws;
    int*   idx    = (int*)wsb;                              // 4 KB
    half8* Bp_hi  = (half8*)(wsb + 4096);                   // 1 MB
    half8* Bp_lo  = (half8*)(wsb + 4096 + 1048576);         // 1 MB
    float* k_part = (float*)(wsb + 4096 + 2097152);         // 8 MB [b][tok][kc][d]
    float* q_part = k_part + (size_t)B_ * NS_ * KS * D_;
    float* v_part = q_part + (size_t)KSQ * B_ * D_;
    float* logits = v_part + (size_t)KS * B_ * NS_;
    float* v_red  = logits + B_ * NS_;

    prep_kernel   <<<40,  256, 0, stream>>>(Wk, mask, idx, Bp_hi, Bp_lo);
    kgemm_kernel  <<<320, 256, 0, stream>>>(hs, Bp_hi, Bp_lo, Wq, Wr, idx, k_part, v_part, q_part);
    logit_kernel  <<<128, 256, 0, stream>>>(k_part, q_part, v_part, bq, bk, br, logits, v_red);
    softmax_kernel<<<8,   128, 0, stream>>>(logits, v_red, out);
}